// Round 1
// baseline (571.773 us; speedup 1.0000x reference)
//
#include <hip/hip_runtime.h>
#include <stdint.h>

typedef float f32x4 __attribute__((ext_vector_type(4)));
typedef short s16x8 __attribute__((ext_vector_type(8)));
typedef short s16x4 __attribute__((ext_vector_type(4)));

#define M_TOTAL 8192
#define DM 1024
#define HID 4096
#define SEQ 1024
#define NH 16
#define DH 64

__device__ __forceinline__ unsigned short f2bf(float f) {
  unsigned int u = __float_as_uint(f);
  u = (u + 0x7fffu + ((u >> 16) & 1u)) >> 16;
  return (unsigned short)u;
}

__device__ __forceinline__ void gload16(const void* g, void* l) {
  __builtin_amdgcn_global_load_lds((__attribute__((address_space(1))) void*)g,
                                   (__attribute__((address_space(3))) void*)l,
                                   16, 0, 0);
}

// ---------------- transpose + cast f32 -> bf16: W[K][N] -> WT[N][K] ----------
__global__ void tcast(const float* __restrict__ W, unsigned short* __restrict__ WT,
                      int K, int N) {
  __shared__ float tile[32][33];
  const int bn = blockIdx.x, bk = blockIdx.y;
  const int tx = threadIdx.x, ty = threadIdx.y;  // 32 x 8
#pragma unroll
  for (int i = 0; i < 32; i += 8)
    tile[ty + i][tx] = W[(size_t)(bk * 32 + ty + i) * N + bn * 32 + tx];
  __syncthreads();
#pragma unroll
  for (int i = 0; i < 32; i += 8)
    WT[(size_t)(bn * 32 + ty + i) * K + bk * 32 + tx] = f2bf(tile[tx][ty + i]);
}

// ---------------- LayerNorm (ddof=1) f32 in -> bf16 out ---------------------
__global__ __launch_bounds__(256)
void ln_kernel(const float* __restrict__ x, const float* __restrict__ alpha,
               const float* __restrict__ beta, unsigned short* __restrict__ out) {
  const int row = blockIdx.x;
  const int t = threadIdx.x;
  const int w = t >> 6, lane = t & 63;
  const float4 v = ((const float4*)(x + (size_t)row * DM))[t];

  float s = v.x + v.y + v.z + v.w;
#pragma unroll
  for (int off = 32; off; off >>= 1) s += __shfl_xor(s, off, 64);
  __shared__ float red1[4];
  __shared__ float red2[4];
  if (lane == 0) red1[w] = s;
  __syncthreads();
  const float mu = (red1[0] + red1[1] + red1[2] + red1[3]) * (1.f / 1024.f);

  const float dx = v.x - mu, dy = v.y - mu, dz = v.z - mu, dw = v.w - mu;
  float sq = dx * dx + dy * dy + dz * dz + dw * dw;
#pragma unroll
  for (int off = 32; off; off >>= 1) sq += __shfl_xor(sq, off, 64);
  if (lane == 0) red2[w] = sq;
  __syncthreads();
  const float var = (red2[0] + red2[1] + red2[2] + red2[3]) * (1.f / 1023.f);
  const float rstd = rsqrtf(var + 1e-6f);

  const float4 a = ((const float4*)alpha)[t];
  const float4 b = ((const float4*)beta)[t];
  s16x4 o;
  o[0] = (short)f2bf(dx * rstd * a.x + b.x);
  o[1] = (short)f2bf(dy * rstd * a.y + b.y);
  o[2] = (short)f2bf(dz * rstd * a.z + b.z);
  o[3] = (short)f2bf(dw * rstd * a.w + b.w);
  *(s16x4*)(out + (size_t)row * DM + 4 * t) = o;
}

// ---------------- GEMM: C[M,N] = A[M,K] (bf16) @ WT[N,K]^T ------------------
// MODE 0: QKV -> scatter to [3][B,H,S,D] bf16 with per-slice bias
// MODE 1: f32 out = res + acc + bias  (residual add; res may alias of)
// MODE 2: bf16 out = gelu_erf(acc + bias)
template <int MODE>
__global__ __launch_bounds__(256)
void gemm_bt(const unsigned short* __restrict__ A, const unsigned short* __restrict__ B,
             int K, int Nout,
             unsigned short* __restrict__ obf, float* of, const float* res,
             const float* __restrict__ bias0, const float* __restrict__ bias1,
             const float* __restrict__ bias2) {
  __shared__ __attribute__((aligned(16))) unsigned short sA[128 * 32];
  __shared__ __attribute__((aligned(16))) unsigned short sB[128 * 32];
  const int t = threadIdx.x;
  const int lane = t & 63, w = t >> 6;
  const int g = lane >> 4, r = lane & 15;
  const int wr = w >> 1, wc = w & 1;
  const int m0 = blockIdx.y * 128, n0 = blockIdx.x * 128;

  f32x4 acc[4][4];
#pragma unroll
  for (int i = 0; i < 4; ++i)
#pragma unroll
    for (int j = 0; j < 4; ++j) acc[i][j] = (f32x4){0.f, 0.f, 0.f, 0.f};

  const int srow = t >> 2;          // 0..63
  const int scol = (t & 3) * 8;     // 0,8,16,24

  for (int kt = 0; kt < K; kt += 32) {
    __syncthreads();
#pragma unroll
    for (int rr = 0; rr < 2; ++rr) {
      const int row = rr * 64 + srow;
      gload16(A + (size_t)(m0 + row) * K + kt + scol, &sA[(size_t)(rr * 256 + w * 64) * 8]);
      gload16(B + (size_t)(n0 + row) * K + kt + scol, &sB[(size_t)(rr * 256 + w * 64) * 8]);
    }
    __syncthreads();
    s16x8 af[4], bfr[4];
#pragma unroll
    for (int i = 0; i < 4; ++i) {
      af[i] = *(const s16x8*)&sA[(wr * 64 + i * 16 + r) * 32 + g * 8];
      bfr[i] = *(const s16x8*)&sB[(wc * 64 + i * 16 + r) * 32 + g * 8];
    }
#pragma unroll
    for (int i = 0; i < 4; ++i)
#pragma unroll
      for (int j = 0; j < 4; ++j)
        acc[i][j] = __builtin_amdgcn_mfma_f32_16x16x32_bf16(af[i], bfr[j], acc[i][j], 0, 0, 0);
  }

#pragma unroll
  for (int i = 0; i < 4; ++i) {
#pragma unroll
    for (int j = 0; j < 4; ++j) {
      const int m = m0 + wr * 64 + i * 16 + 4 * g + j;
#pragma unroll
      for (int nf = 0; nf < 4; ++nf) {
        const int n = n0 + wc * 64 + nf * 16 + r;
        float v = acc[i][nf][j];
        if (MODE == 0) {
          const int which = n >> 10, nn = n & 1023;
          const float* bp = (which == 0) ? bias0 : ((which == 1) ? bias1 : bias2);
          v += bp[nn];
          const int b = m >> 10, s = m & 1023, h = nn >> 6, d = nn & 63;
          obf[(size_t)which * (M_TOTAL * DM) +
              (((size_t)(b * NH + h) * SEQ + s) * DH + d)] = f2bf(v);
        } else if (MODE == 1) {
          v += bias0[n] + res[(size_t)m * Nout + n];
          of[(size_t)m * Nout + n] = v;
        } else {
          v += bias0[n];
          const float gv = 0.5f * v * (1.0f + erff(v * 0.70710678118654752f));
          obf[(size_t)m * Nout + n] = f2bf(gv);
        }
      }
    }
  }
}

// ---------------- flash attention: QKV [3][B,H,S,D] bf16 -> O [B,S,DM] bf16 -
__global__ __launch_bounds__(256)
void attn_kernel(const unsigned short* __restrict__ QKV, unsigned short* __restrict__ O) {
  const unsigned short* Qg = QKV;
  const unsigned short* Kg = QKV + (size_t)M_TOTAL * DM;
  const unsigned short* Vg = QKV + 2 * (size_t)M_TOTAL * DM;
  const int bh = blockIdx.y;        // 0..127
  const int q0 = blockIdx.x * 64;
  const int t = threadIdx.x, w = t >> 6, lane = t & 63;
  const int g = lane >> 4, r = lane & 15;
  const size_t base = (size_t)bh * SEQ * DH;
  const unsigned short* Qb = Qg + base;
  const unsigned short* Kb = Kg + base;
  const unsigned short* Vb = Vg + base;

  __shared__ __attribute__((aligned(16))) unsigned short sK[64][72];
  __shared__ __attribute__((aligned(16))) unsigned short sVT[64][72];
  __shared__ __attribute__((aligned(16))) unsigned short sP[4][16][72];

  s16x8 qf[2];
  {
    const unsigned short* qrow = Qb + (size_t)(q0 + w * 16 + r) * DH;
    qf[0] = *(const s16x8*)(qrow + g * 8);
    qf[1] = *(const s16x8*)(qrow + 32 + g * 8);
  }
  f32x4 oacc[4];
#pragma unroll
  for (int i = 0; i < 4; ++i) oacc[i] = (f32x4){0.f, 0.f, 0.f, 0.f};
  float mrun[4], lrun[4];
#pragma unroll
  for (int j = 0; j < 4; ++j) { mrun[j] = -1e30f; lrun[j] = 0.f; }

  for (int kt = 0; kt < SEQ / 64; ++kt) {
    __syncthreads();
#pragma unroll
    for (int rr = 0; rr < 2; ++rr) {
      const int flat = (rr * 256 + t) * 8;
      const int kr = flat >> 6, kc = flat & 63;
      const s16x8 kvec = *(const s16x8*)(Kb + (size_t)(kt * 64 + kr) * DH + kc);
      *(s16x8*)&sK[kr][kc] = kvec;
      const s16x8 vvec = *(const s16x8*)(Vb + (size_t)(kt * 64 + kr) * DH + kc);
#pragma unroll
      for (int i = 0; i < 8; ++i) sVT[kc + i][kr] = (unsigned short)vvec[i];
    }
    __syncthreads();

    f32x4 s[4];
#pragma unroll
    for (int nf = 0; nf < 4; ++nf) {
      s[nf] = (f32x4){0.f, 0.f, 0.f, 0.f};
#pragma unroll
      for (int ks = 0; ks < 2; ++ks) {
        const s16x8 kf = *(const s16x8*)&sK[nf * 16 + r][ks * 32 + g * 8];
        s[nf] = __builtin_amdgcn_mfma_f32_16x16x32_bf16(qf[ks], kf, s[nf], 0, 0, 0);
      }
    }
#pragma unroll
    for (int nf = 0; nf < 4; ++nf)
#pragma unroll
      for (int j = 0; j < 4; ++j) s[nf][j] *= 0.125f;

    float pm[4], ps[4], alpha_[4], mnew[4];
#pragma unroll
    for (int j = 0; j < 4; ++j) {
      pm[j] = fmaxf(fmaxf(s[0][j], s[1][j]), fmaxf(s[2][j], s[3][j]));
    }
#pragma unroll
    for (int off = 1; off < 16; off <<= 1)
#pragma unroll
      for (int j = 0; j < 4; ++j) pm[j] = fmaxf(pm[j], __shfl_xor(pm[j], off, 64));

    float p[4][4];
#pragma unroll
    for (int j = 0; j < 4; ++j) {
      mnew[j] = fmaxf(mrun[j], pm[j]);
      alpha_[j] = expf(mrun[j] - mnew[j]);
      mrun[j] = mnew[j];
      ps[j] = 0.f;
#pragma unroll
      for (int nf = 0; nf < 4; ++nf) {
        p[nf][j] = expf(s[nf][j] - mnew[j]);
        ps[j] += p[nf][j];
      }
    }
#pragma unroll
    for (int off = 1; off < 16; off <<= 1)
#pragma unroll
      for (int j = 0; j < 4; ++j) ps[j] += __shfl_xor(ps[j], off, 64);
#pragma unroll
    for (int j = 0; j < 4; ++j) lrun[j] = lrun[j] * alpha_[j] + ps[j];
#pragma unroll
    for (int nf2 = 0; nf2 < 4; ++nf2)
#pragma unroll
      for (int j = 0; j < 4; ++j) oacc[nf2][j] *= alpha_[j];

#pragma unroll
    for (int nf = 0; nf < 4; ++nf)
#pragma unroll
      for (int j = 0; j < 4; ++j) sP[w][4 * g + j][nf * 16 + r] = f2bf(p[nf][j]);

    s16x8 pa[2];
#pragma unroll
    for (int ks = 0; ks < 2; ++ks) pa[ks] = *(const s16x8*)&sP[w][r][ks * 32 + g * 8];
#pragma unroll
    for (int nf2 = 0; nf2 < 4; ++nf2)
#pragma unroll
      for (int ks = 0; ks < 2; ++ks) {
        const s16x8 vb = *(const s16x8*)&sVT[nf2 * 16 + r][ks * 32 + g * 8];
        oacc[nf2] = __builtin_amdgcn_mfma_f32_16x16x32_bf16(pa[ks], vb, oacc[nf2], 0, 0, 0);
      }
  }

  const int b = bh >> 4, h = bh & 15;
#pragma unroll
  for (int j = 0; j < 4; ++j) {
    const float inv = 1.f / lrun[j];
    const int srow = q0 + w * 16 + 4 * g + j;
    const size_t orow = ((size_t)(b * SEQ + srow)) * DM + h * DH;
#pragma unroll
    for (int nf2 = 0; nf2 < 4; ++nf2)
      O[orow + nf2 * 16 + r] = f2bf(oacc[nf2][j] * inv);
  }
}

// ---------------------------------------------------------------------------
extern "C" void kernel_launch(void* const* d_in, const int* in_sizes, int n_in,
                              void* d_out, int out_size, void* d_ws, size_t ws_size,
                              hipStream_t stream) {
  const float* x   = (const float*)d_in[0];
  const float* al1 = (const float*)d_in[1];
  const float* be1 = (const float*)d_in[2];
  const float* al2 = (const float*)d_in[3];
  const float* be2 = (const float*)d_in[4];
  const float* wq  = (const float*)d_in[5];
  const float* bq  = (const float*)d_in[6];
  const float* wk  = (const float*)d_in[7];
  const float* bk  = (const float*)d_in[8];
  const float* wv  = (const float*)d_in[9];
  const float* bv  = (const float*)d_in[10];
  const float* wo  = (const float*)d_in[11];
  const float* bo  = (const float*)d_in[12];
  const float* w1  = (const float*)d_in[13];
  const float* b1  = (const float*)d_in[14];
  const float* w2  = (const float*)d_in[15];
  const float* b2  = (const float*)d_in[16];
  float* dout = (float*)d_out;

  unsigned short* ws = (unsigned short*)d_ws;
  size_t off = 0;
  auto alloc = [&](size_t n) { unsigned short* p = ws + off; off += n; return p; };
  unsigned short* WTqkv = alloc((size_t)3072 * 1024);
  unsigned short* WTo   = alloc((size_t)1024 * 1024);
  unsigned short* WT1   = alloc((size_t)4096 * 1024);
  unsigned short* WT2   = alloc((size_t)1024 * 4096);
  unsigned short* xn    = alloc((size_t)M_TOTAL * DM);
  unsigned short* QKVb  = alloc((size_t)3 * M_TOTAL * DM);
  unsigned short* attn  = alloc((size_t)M_TOTAL * DM);
  unsigned short* h1    = alloc((size_t)M_TOTAL * HID);
  (void)ws_size; (void)in_sizes; (void)n_in; (void)out_size;

  const dim3 tb(32, 8);
  tcast<<<dim3(32, 32), tb, 0, stream>>>(wq, WTqkv, 1024, 1024);
  tcast<<<dim3(32, 32), tb, 0, stream>>>(wk, WTqkv + (size_t)1024 * 1024, 1024, 1024);
  tcast<<<dim3(32, 32), tb, 0, stream>>>(wv, WTqkv + (size_t)2048 * 1024, 1024, 1024);
  tcast<<<dim3(32, 32), tb, 0, stream>>>(wo, WTo, 1024, 1024);
  tcast<<<dim3(128, 32), tb, 0, stream>>>(w1, WT1, 1024, 4096);
  tcast<<<dim3(32, 128), tb, 0, stream>>>(w2, WT2, 4096, 1024);

  // LN1: x -> xn (bf16)
  ln_kernel<<<M_TOTAL, 256, 0, stream>>>(x, al1, be1, xn);
  // QKV projection (fused): [8192,1024] @ [1024,3072] -> Q,K,V [B,H,S,D]
  gemm_bt<0><<<dim3(24, 64), 256, 0, stream>>>(xn, WTqkv, 1024, 3072,
                                               QKVb, nullptr, nullptr, bq, bk, bv);
  // attention
  attn_kernel<<<dim3(16, 128), 256, 0, stream>>>(QKVb, attn);
  // O projection + residual: dout = x + attn @ Wo + bo
  gemm_bt<1><<<dim3(8, 64), 256, 0, stream>>>(attn, WTo, 1024, 1024,
                                              nullptr, dout, x, bo, nullptr, nullptr);
  // LN2: dout -> xn (bf16)
  ln_kernel<<<M_TOTAL, 256, 0, stream>>>(dout, al2, be2, xn);
  // MLP1 + GELU: h1 = gelu(xn @ W1 + b1)
  gemm_bt<2><<<dim3(32, 64), 256, 0, stream>>>(xn, WT1, 1024, 4096,
                                               h1, nullptr, nullptr, b1, nullptr, nullptr);
  // MLP2 + residual: dout = dout + h1 @ W2 + b2
  gemm_bt<1><<<dim3(8, 64), 256, 0, stream>>>(h1, WT2, 4096, 1024,
                                              nullptr, dout, dout, b2, nullptr, nullptr);
}

// Round 2
// 498.401 us; speedup vs baseline: 1.1472x; 1.1472x over previous
//
#include <hip/hip_runtime.h>
#include <stdint.h>

typedef float f32x4 __attribute__((ext_vector_type(4)));
typedef short s16x8 __attribute__((ext_vector_type(8)));
typedef short s16x4 __attribute__((ext_vector_type(4)));
typedef unsigned int u32x4 __attribute__((ext_vector_type(4)));

#define M_TOTAL 8192
#define DM 1024
#define HID 4096
#define SEQ 1024
#define NH 16
#define DH 64

__device__ __forceinline__ unsigned short f2bf(float f) {
  unsigned int u = __float_as_uint(f);
  u = (u + 0x7fffu + ((u >> 16) & 1u)) >> 16;
  return (unsigned short)u;
}

__device__ __forceinline__ void gload16(const void* g, void* l) {
  __builtin_amdgcn_global_load_lds((__attribute__((address_space(1))) void*)g,
                                   (__attribute__((address_space(3))) void*)l,
                                   16, 0, 0);
}

// ---------------- transpose + cast f32 -> bf16: W[K][N] -> WT[N][K] ----------
__global__ void tcast(const float* __restrict__ W, unsigned short* __restrict__ WT,
                      int K, int N) {
  __shared__ float tile[32][33];
  const int bn = blockIdx.x, bk = blockIdx.y;
  const int tx = threadIdx.x, ty = threadIdx.y;  // 32 x 8
#pragma unroll
  for (int i = 0; i < 32; i += 8)
    tile[ty + i][tx] = W[(size_t)(bk * 32 + ty + i) * N + bn * 32 + tx];
  __syncthreads();
#pragma unroll
  for (int i = 0; i < 32; i += 8)
    WT[(size_t)(bn * 32 + ty + i) * K + bk * 32 + tx] = f2bf(tile[tx][ty + i]);
}

// ---------------- V [BH][S][D] bf16 -> VT [BH][D][S] bf16 -------------------
__global__ __launch_bounds__(256)
void vtrans(const unsigned short* __restrict__ V, unsigned short* __restrict__ VT) {
  __shared__ unsigned short tile[64][65];
  const int bh = blockIdx.y, s0 = blockIdx.x * 64;
  const int t = threadIdx.x;
  const int sr = t >> 3, c0 = (t & 7) * 8;
#pragma unroll
  for (int it = 0; it < 2; ++it) {
    const int s = it * 32 + sr;
    const s16x8 v = *(const s16x8*)(V + ((size_t)bh * SEQ + s0 + s) * DH + c0);
#pragma unroll
    for (int i = 0; i < 8; ++i) tile[c0 + i][s] = (unsigned short)v[i];
  }
  __syncthreads();
#pragma unroll
  for (int it = 0; it < 2; ++it) {
    const int d = it * 32 + sr;
    s16x8 o;
#pragma unroll
    for (int i = 0; i < 8; ++i) o[i] = (short)tile[d][c0 + i];
    *(s16x8*)(VT + ((size_t)bh * DH + d) * SEQ + s0 + c0) = o;
  }
}

// ---------------- LayerNorm (ddof=1) f32 in -> bf16 out ---------------------
__global__ __launch_bounds__(256)
void ln_kernel(const float* __restrict__ x, const float* __restrict__ alpha,
               const float* __restrict__ beta, unsigned short* __restrict__ out) {
  const int row = blockIdx.x;
  const int t = threadIdx.x;
  const int w = t >> 6, lane = t & 63;
  const float4 v = ((const float4*)(x + (size_t)row * DM))[t];

  float s = v.x + v.y + v.z + v.w;
#pragma unroll
  for (int off = 32; off; off >>= 1) s += __shfl_xor(s, off, 64);
  __shared__ float red1[4];
  __shared__ float red2[4];
  if (lane == 0) red1[w] = s;
  __syncthreads();
  const float mu = (red1[0] + red1[1] + red1[2] + red1[3]) * (1.f / 1024.f);

  const float dx = v.x - mu, dy = v.y - mu, dz = v.z - mu, dw = v.w - mu;
  float sq = dx * dx + dy * dy + dz * dz + dw * dw;
#pragma unroll
  for (int off = 32; off; off >>= 1) sq += __shfl_xor(sq, off, 64);
  if (lane == 0) red2[w] = sq;
  __syncthreads();
  const float var = (red2[0] + red2[1] + red2[2] + red2[3]) * (1.f / 1023.f);
  const float rstd = rsqrtf(var + 1e-6f);

  const float4 a = ((const float4*)alpha)[t];
  const float4 b = ((const float4*)beta)[t];
  s16x4 o;
  o[0] = (short)f2bf(dx * rstd * a.x + b.x);
  o[1] = (short)f2bf(dy * rstd * a.y + b.y);
  o[2] = (short)f2bf(dz * rstd * a.z + b.z);
  o[3] = (short)f2bf(dw * rstd * a.w + b.w);
  *(s16x4*)(out + (size_t)row * DM + 4 * t) = o;
}

// ---------------- GEMM: C[M,N] = A[M,K] (bf16) @ WT[N,K]^T ------------------
template <int MODE>
__global__ __launch_bounds__(256)
void gemm_bt(const unsigned short* __restrict__ A, const unsigned short* __restrict__ B,
             int K, int Nout,
             unsigned short* __restrict__ obf, float* of, const float* res,
             const float* __restrict__ bias0, const float* __restrict__ bias1,
             const float* __restrict__ bias2) {
  __shared__ __attribute__((aligned(16))) unsigned short sA[128 * 32];
  __shared__ __attribute__((aligned(16))) unsigned short sB[128 * 32];
  const int t = threadIdx.x;
  const int lane = t & 63, w = t >> 6;
  const int g = lane >> 4, r = lane & 15;
  const int wr = w >> 1, wc = w & 1;
  const int m0 = blockIdx.y * 128, n0 = blockIdx.x * 128;

  f32x4 acc[4][4];
#pragma unroll
  for (int i = 0; i < 4; ++i)
#pragma unroll
    for (int j = 0; j < 4; ++j) acc[i][j] = (f32x4){0.f, 0.f, 0.f, 0.f};

  const int srow = t >> 2;
  const int scol = (t & 3) * 8;

  for (int kt = 0; kt < K; kt += 32) {
    __syncthreads();
#pragma unroll
    for (int rr = 0; rr < 2; ++rr) {
      const int row = rr * 64 + srow;
      gload16(A + (size_t)(m0 + row) * K + kt + scol, &sA[(size_t)(rr * 256 + w * 64) * 8]);
      gload16(B + (size_t)(n0 + row) * K + kt + scol, &sB[(size_t)(rr * 256 + w * 64) * 8]);
    }
    __syncthreads();
    s16x8 af[4], bfr[4];
#pragma unroll
    for (int i = 0; i < 4; ++i) {
      af[i] = *(const s16x8*)&sA[(wr * 64 + i * 16 + r) * 32 + g * 8];
      bfr[i] = *(const s16x8*)&sB[(wc * 64 + i * 16 + r) * 32 + g * 8];
    }
#pragma unroll
    for (int i = 0; i < 4; ++i)
#pragma unroll
      for (int j = 0; j < 4; ++j)
        acc[i][j] = __builtin_amdgcn_mfma_f32_16x16x32_bf16(af[i], bfr[j], acc[i][j], 0, 0, 0);
  }

#pragma unroll
  for (int i = 0; i < 4; ++i) {
#pragma unroll
    for (int j = 0; j < 4; ++j) {
      const int m = m0 + wr * 64 + i * 16 + 4 * g + j;
#pragma unroll
      for (int nf = 0; nf < 4; ++nf) {
        const int n = n0 + wc * 64 + nf * 16 + r;
        float v = acc[i][nf][j];
        if (MODE == 0) {
          const int which = n >> 10, nn = n & 1023;
          const float* bp = (which == 0) ? bias0 : ((which == 1) ? bias1 : bias2);
          v += bp[nn];
          const int b = m >> 10, s = m & 1023, h = nn >> 6, d = nn & 63;
          obf[(size_t)which * (M_TOTAL * DM) +
              (((size_t)(b * NH + h) * SEQ + s) * DH + d)] = f2bf(v);
        } else if (MODE == 1) {
          v += bias0[n] + res[(size_t)m * Nout + n];
          of[(size_t)m * Nout + n] = v;
        } else {
          v += bias0[n];
          const float gv = 0.5f * v * (1.0f + erff(v * 0.70710678118654752f));
          obf[(size_t)m * Nout + n] = f2bf(gv);
        }
      }
    }
  }
}

// ---------------- flash attention (swapped-QK, swizzled LDS, prefetch) ------
// QKV: [3][BH][S][D] bf16 (Q,K slices used); VT: [BH][D][S] bf16
__global__ __launch_bounds__(256)
void attn_kernel(const unsigned short* __restrict__ QKV,
                 const unsigned short* __restrict__ VT,
                 unsigned short* __restrict__ O) {
  const unsigned short* Qg = QKV;
  const unsigned short* Kg = QKV + (size_t)M_TOTAL * DM;
  const int bh = blockIdx.y;
  const int q0 = blockIdx.x * 64;
  const int t = threadIdx.x, w = t >> 6, lane = t & 63;
  const int g = lane >> 4, r = lane & 15;
  const unsigned short* Qb = Qg + (size_t)bh * SEQ * DH;
  const unsigned short* Kb = Kg + (size_t)bh * SEQ * DH;
  const unsigned short* VTb = VT + (size_t)bh * DH * SEQ;

  __shared__ __attribute__((aligned(16))) unsigned short sK[2][64 * 64];
  __shared__ __attribute__((aligned(16))) unsigned short sV[2][64 * 64];

  // Q fragment (B-operand): q = q0 + w*16 + r
  s16x8 qf[2];
  {
    const unsigned short* qrow = Qb + (size_t)(q0 + w * 16 + r) * DH;
    qf[0] = *(const s16x8*)(qrow + g * 8);
    qf[1] = *(const s16x8*)(qrow + 32 + g * 8);
  }

  f32x4 oacc[4];
#pragma unroll
  for (int i = 0; i < 4; ++i) oacc[i] = (f32x4){0.f, 0.f, 0.f, 0.f};
  float mrun = -1e30f, lrun = 0.f;

  auto stage = [&](int buf, int kt) {
#pragma unroll
    for (int s2 = 0; s2 < 2; ++s2) {
      const int f = s2 * 256 + t;
      const int row = f >> 3, u = (f & 7) ^ (row & 7);
      gload16(Kb + (size_t)(kt * 64 + row) * DH + u * 8, &sK[buf][f * 8]);
      gload16(VTb + (size_t)row * SEQ + kt * 64 + u * 8, &sV[buf][f * 8]);
    }
  };

  stage(0, 0);
  __syncthreads();

  for (int kt = 0; kt < SEQ / 64; ++kt) {
    const int cur = kt & 1;
    if (kt < SEQ / 64 - 1) stage(cur ^ 1, kt + 1);

    // QK^T swapped: sc[nf][j] = S[q=r][k = nf*16 + 4g + j]
    f32x4 sc[4];
#pragma unroll
    for (int nf = 0; nf < 4; ++nf) {
      sc[nf] = (f32x4){0.f, 0.f, 0.f, 0.f};
      const int rowk = nf * 16 + r;
#pragma unroll
      for (int ks = 0; ks < 2; ++ks) {
        const int u = (4 * ks + g) ^ (rowk & 7);
        const s16x8 kf = *(const s16x8*)&sK[cur][rowk * 64 + u * 8];
        sc[nf] = __builtin_amdgcn_mfma_f32_16x16x32_bf16(kf, qf[ks], sc[nf], 0, 0, 0);
      }
    }

    float pm = -1e30f;
#pragma unroll
    for (int nf = 0; nf < 4; ++nf)
#pragma unroll
      for (int j = 0; j < 4; ++j) {
        sc[nf][j] *= 0.125f;
        pm = fmaxf(pm, sc[nf][j]);
      }
    pm = fmaxf(pm, __shfl_xor(pm, 16, 64));
    pm = fmaxf(pm, __shfl_xor(pm, 32, 64));

    const float mnew = fmaxf(mrun, pm);
    const float alpha = __expf(mrun - mnew);
    mrun = mnew;

    float p[4][4];
    float ps = 0.f;
#pragma unroll
    for (int nf = 0; nf < 4; ++nf)
#pragma unroll
      for (int j = 0; j < 4; ++j) {
        p[nf][j] = __expf(sc[nf][j] - mnew);
        ps += p[nf][j];
      }
    ps += __shfl_xor(ps, 16, 64);
    ps += __shfl_xor(ps, 32, 64);
    lrun = lrun * alpha + ps;

    // rescale O rows (q = 4g + j) by that row's alpha
    float ao[4];
#pragma unroll
    for (int j = 0; j < 4; ++j) ao[j] = __shfl(alpha, 4 * g + j, 64);
#pragma unroll
    for (int nf2 = 0; nf2 < 4; ++nf2)
#pragma unroll
      for (int j = 0; j < 4; ++j) oacc[nf2][j] *= ao[j];

    // pack P to bf16 pairs: pk[nf][jp] holds k = nf*16+4g+2jp {lo,hi}
    unsigned int pk[4][2];
#pragma unroll
    for (int nf = 0; nf < 4; ++nf)
#pragma unroll
      for (int jp = 0; jp < 2; ++jp)
        pk[nf][jp] = (unsigned int)f2bf(p[nf][2 * jp]) |
                     ((unsigned int)f2bf(p[nf][2 * jp + 1]) << 16);

    // redistribute to A-fragment: pa[ks] holds P[q=r][k = 32ks + 8g + i]
    unsigned int pa32[2][4];
#pragma unroll
    for (int ks = 0; ks < 2; ++ks)
#pragma unroll
      for (int q2 = 0; q2 < 4; ++q2) {
        const int src = r + 32 * (g & 1) + 16 * (q2 >> 1);
        const unsigned int a = (unsigned int)__shfl((int)pk[2 * ks][q2 & 1], src, 64);
        const unsigned int b = (unsigned int)__shfl((int)pk[2 * ks + 1][q2 & 1], src, 64);
        pa32[ks][q2] = (g >> 1) ? b : a;
      }
    s16x8 pa[2];
#pragma unroll
    for (int ks = 0; ks < 2; ++ks) {
      u32x4 pw;
      pw[0] = pa32[ks][0]; pw[1] = pa32[ks][1];
      pw[2] = pa32[ks][2]; pw[3] = pa32[ks][3];
      pa[ks] = __builtin_bit_cast(s16x8, pw);
    }

    // PV: oacc[nf2] (d = nf2*16 + r), rows q = 4g + j
#pragma unroll
    for (int nf2 = 0; nf2 < 4; ++nf2) {
      const int rowd = nf2 * 16 + r;
#pragma unroll
      for (int ks = 0; ks < 2; ++ks) {
        const int u = (4 * ks + g) ^ (rowd & 7);
        const s16x8 vb = *(const s16x8*)&sV[cur][rowd * 64 + u * 8];
        oacc[nf2] = __builtin_amdgcn_mfma_f32_16x16x32_bf16(pa[ks], vb, oacc[nf2], 0, 0, 0);
      }
    }
    __syncthreads();
  }

  const int b = bh >> 4, h = bh & 15;
  const float linv = 1.f / lrun;
#pragma unroll
  for (int j = 0; j < 4; ++j) {
    const float lo = __shfl(linv, 4 * g + j, 64);
    const int q = q0 + w * 16 + 4 * g + j;
    const size_t orow = ((size_t)(b * SEQ + q)) * DM + h * DH;
#pragma unroll
    for (int nf2 = 0; nf2 < 4; ++nf2)
      O[orow + nf2 * 16 + r] = f2bf(oacc[nf2][j] * lo);
  }
}

// ---------------------------------------------------------------------------
extern "C" void kernel_launch(void* const* d_in, const int* in_sizes, int n_in,
                              void* d_out, int out_size, void* d_ws, size_t ws_size,
                              hipStream_t stream) {
  const float* x   = (const float*)d_in[0];
  const float* al1 = (const float*)d_in[1];
  const float* be1 = (const float*)d_in[2];
  const float* al2 = (const float*)d_in[3];
  const float* be2 = (const float*)d_in[4];
  const float* wq  = (const float*)d_in[5];
  const float* bq  = (const float*)d_in[6];
  const float* wk  = (const float*)d_in[7];
  const float* bk  = (const float*)d_in[8];
  const float* wv  = (const float*)d_in[9];
  const float* bv  = (const float*)d_in[10];
  const float* wo  = (const float*)d_in[11];
  const float* bo  = (const float*)d_in[12];
  const float* w1  = (const float*)d_in[13];
  const float* b1  = (const float*)d_in[14];
  const float* w2  = (const float*)d_in[15];
  const float* b2  = (const float*)d_in[16];
  float* dout = (float*)d_out;

  unsigned short* ws = (unsigned short*)d_ws;
  size_t off = 0;
  auto alloc = [&](size_t n) { unsigned short* p = ws + off; off += n; return p; };
  unsigned short* WTqkv = alloc((size_t)3072 * 1024);
  unsigned short* WTo   = alloc((size_t)1024 * 1024);
  unsigned short* WT1   = alloc((size_t)4096 * 1024);
  unsigned short* WT2   = alloc((size_t)1024 * 4096);
  unsigned short* xn    = alloc((size_t)M_TOTAL * DM);
  unsigned short* QKVb  = alloc((size_t)3 * M_TOTAL * DM);
  unsigned short* VTb   = alloc((size_t)M_TOTAL * DM);
  unsigned short* attn  = alloc((size_t)M_TOTAL * DM);
  unsigned short* h1    = alloc((size_t)M_TOTAL * HID);
  (void)ws_size; (void)in_sizes; (void)n_in; (void)out_size;

  const dim3 tb(32, 8);
  tcast<<<dim3(32, 32), tb, 0, stream>>>(wq, WTqkv, 1024, 1024);
  tcast<<<dim3(32, 32), tb, 0, stream>>>(wk, WTqkv + (size_t)1024 * 1024, 1024, 1024);
  tcast<<<dim3(32, 32), tb, 0, stream>>>(wv, WTqkv + (size_t)2048 * 1024, 1024, 1024);
  tcast<<<dim3(32, 32), tb, 0, stream>>>(wo, WTo, 1024, 1024);
  tcast<<<dim3(128, 32), tb, 0, stream>>>(w1, WT1, 1024, 4096);
  tcast<<<dim3(32, 128), tb, 0, stream>>>(w2, WT2, 4096, 1024);

  // LN1: x -> xn (bf16)
  ln_kernel<<<M_TOTAL, 256, 0, stream>>>(x, al1, be1, xn);
  // QKV projection (fused)
  gemm_bt<0><<<dim3(24, 64), 256, 0, stream>>>(xn, WTqkv, 1024, 3072,
                                               QKVb, nullptr, nullptr, bq, bk, bv);
  // V -> V^T
  vtrans<<<dim3(16, 128), 256, 0, stream>>>(QKVb + 2 * (size_t)M_TOTAL * DM, VTb);
  // attention
  attn_kernel<<<dim3(16, 128), 256, 0, stream>>>(QKVb, VTb, attn);
  // O projection + residual: dout = x + attn @ Wo + bo
  gemm_bt<1><<<dim3(8, 64), 256, 0, stream>>>(attn, WTo, 1024, 1024,
                                              nullptr, dout, x, bo, nullptr, nullptr);
  // LN2: dout -> xn (bf16)
  ln_kernel<<<M_TOTAL, 256, 0, stream>>>(dout, al2, be2, xn);
  // MLP1 + GELU
  gemm_bt<2><<<dim3(32, 64), 256, 0, stream>>>(xn, WT1, 1024, 4096,
                                               h1, nullptr, nullptr, b1, nullptr, nullptr);
  // MLP2 + residual
  gemm_bt<1><<<dim3(8, 64), 256, 0, stream>>>(h1, WT2, 4096, 1024,
                                              nullptr, dout, dout, b2, nullptr, nullptr);
}